// Round 6
// baseline (3306.791 us; speedup 1.0000x reference)
//
#include <hip/hip_runtime.h>
#include <math.h>
#include <stdint.h>

namespace {
constexpr int N_    = 2048;
constexpr int H_    = 800;
constexpr int SROW  = 832;            // spike row stride (bytes), K padded to 64
constexpr int IN_   = 28;
constexpr int TENC  = 28;
constexpr int TTOT  = 78;             // 28 encode + 50 decode
constexpr int ONUM  = 10;
constexpr int HBLK  = 200;            // 25 it-tiles x 8 ngroups
constexpr int NBLK  = 208;            // + 8 output blocks
constexpr int LROW  = 848;            // LDS B row stride (bytes): 832+16 -> 2-way banks only
constexpr int LPL   = 32 * LROW;      // 27136 B per digit plane
constexpr int SMEM_B = 4 * LPL;       // 108544
constexpr int SMEM_W = IN_ * 32 * 4;  // Wi tile 3584
constexpr int SMEM_TOT = SMEM_B + SMEM_W;  // 112128 <= 160K -> HW enforces 1 block/CU
}

typedef __attribute__((ext_vector_type(4))) int v4i;

__device__ __forceinline__ v4i ld16(const int8_t* p) { return *(const v4i*)(p); }

// balanced base-256 digits of round(w * 2^32); exact for |w| < ~0.49
__device__ __forceinline__ void digitize(float w, int8_t d[4]) {
    double dd = (double)w * 4294967296.0;
    long long r = (long long)rint(dd);
    int8_t d0 = (int8_t)(r & 255); r = (r - (long long)d0) >> 8;
    int8_t d1 = (int8_t)(r & 255); r = (r - (long long)d1) >> 8;
    int8_t d2 = (int8_t)(r & 255); r = (r - (long long)d2) >> 8;
    long long r3 = r; r3 = r3 > 127 ? 127 : (r3 < -128 ? -128 : r3);
    d[0] = d0; d[1] = d1; d[2] = d2; d[3] = (int8_t)r3;
}

// --------------------------- grid barrier ----------------------------------
// Sense-reversing, device(agent)-scope. Ends each launch with cnt==0; gen is
// monotonic across launches (compared relatively, wrap-safe).
__device__ unsigned g_bar_cnt = 0;
__device__ unsigned g_bar_gen = 0;

__device__ __forceinline__ void grid_barrier() {
    __syncthreads();   // drains this wave-group's vmcnt: spike stores are in L2
    if (threadIdx.x == 0) {
        unsigned gen = __hip_atomic_load(&g_bar_gen, __ATOMIC_RELAXED, __HIP_MEMORY_SCOPE_AGENT);
        unsigned arr = __hip_atomic_fetch_add(&g_bar_cnt, 1u, __ATOMIC_ACQ_REL, __HIP_MEMORY_SCOPE_AGENT);
        if (arr == (unsigned)(NBLK - 1)) {
            __hip_atomic_store(&g_bar_cnt, 0u, __ATOMIC_RELAXED, __HIP_MEMORY_SCOPE_AGENT);
            __hip_atomic_fetch_add(&g_bar_gen, 1u, __ATOMIC_RELEASE, __HIP_MEMORY_SCOPE_AGENT);
        } else {
            while (__hip_atomic_load(&g_bar_gen, __ATOMIC_RELAXED, __HIP_MEMORY_SCOPE_AGENT) == gen)
                __builtin_amdgcn_s_sleep(8);
            // one acquire to invalidate stale cache lines (cross-XCD)
            (void)__hip_atomic_load(&g_bar_gen, __ATOMIC_ACQUIRE, __HIP_MEMORY_SCOPE_AGENT);
        }
    }
    __syncthreads();
}

// ---------------------------------------------------------------------------
// Persistent LSNN kernel: 200 hidden blocks (32 neurons x 256 samples each,
// wave = 32 samples x 32 neurons) + 8 output blocks (256 samples each).
// Weights digitized once into LDS; hm/hb/prev-spike state in registers.
// ---------------------------------------------------------------------------
__global__ __launch_bounds__(512, 2)
void lsnn_persist(const float* __restrict__ x,
                  const float* __restrict__ Wi,
                  const float* __restrict__ b_i2h,
                  const float* __restrict__ Wh,
                  const float* __restrict__ b_h2h,
                  const float* __restrict__ Wo,
                  const float* __restrict__ b_h2o,
                  const float* __restrict__ tau_h,
                  const float* __restrict__ tau_o,
                  int8_t* spk0, int8_t* spk1,
                  float* __restrict__ out)
{
    extern __shared__ __align__(16) int8_t smem[];
    int8_t* Bl = smem;                       // [4 planes][32 rows][848]
    float*  wl = (float*)(smem + SMEM_B);    // [28][32]

    const int bid  = blockIdx.x;
    const bool is_o = (bid >= HBLK);
    const int it   = is_o ? 0 : (bid % 25);
    const int ng   = is_o ? (bid - HBLK) : (bid / 25);
    const int i0   = it * 32;
    const int wv   = threadIdx.x >> 6;
    const int lane = threadIdx.x & 63;
    const int quad = lane >> 4;
    const int col  = lane & 15;
    const int n0   = ng * 256 + wv * 32;

    // ---- digitize this block's weights into LDS (once) ----
    for (int e = threadIdx.x; e < 32 * SROW; e += 512) {
        int r = e / SROW, k = e - r * SROW;
        float w = 0.f;
        if (k < H_) {
            if (!is_o)          w = Wh[(size_t)(i0 + r) * H_ + k];
            else if (r < ONUM)  w = Wo[(size_t)r * H_ + k];
        }
        int8_t d[4]; digitize(w, d);
        int off = r * LROW + k;
        Bl[off] = d[0]; Bl[LPL + off] = d[1]; Bl[2 * LPL + off] = d[2]; Bl[3 * LPL + off] = d[3];
    }
    if (!is_o) {
        for (int e = threadIdx.x; e < IN_ * 32; e += 512) {
            int c = e >> 5, il = e & 31;
            wl[c * 32 + il] = Wi[(size_t)(i0 + il) * IN_ + c];
        }
    }
    // ---- zero spike buffers (it==0 hidden blocks cover all samples) ----
    if (!is_o && it == 0) {
        uint4 z = {0u, 0u, 0u, 0u};
        size_t base = (size_t)ng * 256 * SROW;
        for (int e = threadIdx.x; e < 256 * SROW / 16; e += 512) {
            ((uint4*)(spk0 + base))[e] = z;
            ((uint4*)(spk1 + base))[e] = z;
        }
    }

    // ---- per-lane constants & register state ----
    const float alpha = (float)exp((double)(-1.0f / 20.0f));
    const float onem  = 1.0f - alpha;
    const double INV32 = 1.0 / 4294967296.0;

    float hm[2][2][4] = {}, hbv[2][2][4], psp[2][2][4] = {};
    float roB[2] = {}, biB[2] = {}, bhB[2] = {};
    float om[2][4] = {}, osp[2][4] = {}, obb[2][4], cnt[2][4] = {};
    float roO = 0.f, boO = 0.f;

    if (!is_o) {
        #pragma unroll
        for (int b = 0; b < 2; ++b) {
            int i = i0 + b * 16 + col;
            float arg = -1.0f / tau_h[i];
            roB[b] = (float)exp((double)arg);
            biB[b] = b_i2h[i]; bhB[b] = b_h2h[i];
        }
        #pragma unroll
        for (int a = 0; a < 2; ++a)
            #pragma unroll
            for (int b = 0; b < 2; ++b)
                #pragma unroll
                for (int r = 0; r < 4; ++r) hbv[a][b][r] = 0.01f;
    } else {
        if (col < ONUM) {
            float arg = -1.0f / tau_o[col];
            roO = (float)exp((double)arg);
            boO = b_h2o[col];
        }
        #pragma unroll
        for (int a = 0; a < 2; ++a)
            #pragma unroll
            for (int r = 0; r < 4; ++r) obb[a][r] = 0.01f;
    }

    __syncthreads();
    grid_barrier();

    // ---- time loop ----
    for (int t = 0; t <= TTOT; ++t) {
        const int8_t* rd = (t & 1) ? spk1 : spk0;
        int8_t*       wr = (t & 1) ? spk0 : spk1;

        if (!is_o && t < TTOT) {
            // input projection (encode steps only): fp64 exact, fp32-rounded once
            float inpf[2][2][4] = {};
            if (t < TENC) {
                #pragma unroll
                for (int a = 0; a < 2; ++a) {
                    #pragma unroll
                    for (int r = 0; r < 4; ++r) {
                        int n = n0 + a * 16 + quad * 4 + r;
                        const float* xp = x + (size_t)n * 784 + t;
                        double s0 = 0.0, s1 = 0.0;
                        #pragma unroll
                        for (int c = 0; c < IN_; ++c) {
                            double xv = (double)xp[c * TENC];
                            s0 += xv * (double)wl[c * 32 + col];
                            s1 += xv * (double)wl[c * 32 + 16 + col];
                        }
                        inpf[a][0][r] = (float)s0;
                        inpf[a][1][r] = (float)s1;
                    }
                }
            }

            // hidden GEMM: A (spikes) from global, B (digits) from LDS
            v4i acc4[2][2][4] = {};
            const int8_t* pa0 = rd + (size_t)(n0 + col) * SROW + quad * 16;
            const int8_t* pa1 = pa0 + (size_t)16 * SROW;
            const int8_t* pb  = Bl + col * LROW + quad * 16;
            v4i a0c = ld16(pa0), a1c = ld16(pa1);
            v4i a0n = ld16(pa0 + 64), a1n = ld16(pa1 + 64);
            for (int c = 0; c < 13; ++c) {
                v4i a0f = a0n, a1f = a1n;
                if (c < 11) { a0f = ld16(pa0 + (c + 2) * 64); a1f = ld16(pa1 + (c + 2) * 64); }
                const int off = c * 64;
                #pragma unroll
                for (int k = 0; k < 4; ++k) {
                    v4i b0 = *(const v4i*)(pb + k * LPL + off);
                    v4i b1 = *(const v4i*)(pb + k * LPL + 16 * LROW + off);
                    acc4[0][0][k] = __builtin_amdgcn_mfma_i32_16x16x64_i8(a0c, b0, acc4[0][0][k], 0, 0, 0);
                    acc4[0][1][k] = __builtin_amdgcn_mfma_i32_16x16x64_i8(a0c, b1, acc4[0][1][k], 0, 0, 0);
                    acc4[1][0][k] = __builtin_amdgcn_mfma_i32_16x16x64_i8(a1c, b0, acc4[1][0][k], 0, 0, 0);
                    acc4[1][1][k] = __builtin_amdgcn_mfma_i32_16x16x64_i8(a1c, b1, acc4[1][1][k], 0, 0, 0);
                }
                a0c = a0n; a1c = a1n; a0n = a0f; a1n = a1f;
            }

            // hidden epilogue: fp32, reference order, no FMA; state in registers
            {
                #pragma clang fp contract(off)
                #pragma unroll
                for (int a = 0; a < 2; ++a) {
                    #pragma unroll
                    for (int b = 0; b < 2; ++b) {
                        int i = i0 + b * 16 + col;
                        #pragma unroll
                        for (int r = 0; r < 4; ++r) {
                            int n = n0 + a * 16 + quad * 4 + r;
                            int64_t tot = ((int64_t)acc4[a][b][3][r] << 24)
                                        + ((int64_t)acc4[a][b][2][r] << 16)
                                        + ((int64_t)acc4[a][b][1][r] << 8)
                                        +  (int64_t)acc4[a][b][0][r];
                            float rec = (float)((double)tot * INV32);
                            float h_in = ((inpf[a][b][r] + biB[b]) + rec) + bhB[b];
                            float sp = psp[a][b][r];
                            float ro = roB[b];
                            float bnew = (ro * hbv[a][b][r]) + ((1.0f - ro) * sp);
                            float B = 0.01f + (1.8f * bnew);
                            float mem = ((hm[a][b][r] * alpha) + (onem * h_in)) - (B * sp);
                            float s = (mem - B) > 0.f ? 1.f : 0.f;
                            hbv[a][b][r] = bnew; hm[a][b][r] = mem; psp[a][b][r] = s;
                            wr[(size_t)n * SROW + i] = (int8_t)s;
                        }
                    }
                }
            }
        }

        if (is_o && t >= 1) {
            // output-layer GEMM for output-step t-1 (consumes h_spk[t-1] = rd)
            v4i oacc[2][4] = {};
            const int8_t* pa0 = rd + (size_t)(n0 + col) * SROW + quad * 16;
            const int8_t* pa1 = pa0 + (size_t)16 * SROW;
            const int8_t* pb  = Bl + col * LROW + quad * 16;
            v4i a0c = ld16(pa0), a1c = ld16(pa1);
            v4i a0n = ld16(pa0 + 64), a1n = ld16(pa1 + 64);
            for (int c = 0; c < 13; ++c) {
                v4i a0f = a0n, a1f = a1n;
                if (c < 11) { a0f = ld16(pa0 + (c + 2) * 64); a1f = ld16(pa1 + (c + 2) * 64); }
                const int off = c * 64;
                #pragma unroll
                for (int k = 0; k < 4; ++k) {
                    v4i bo = *(const v4i*)(pb + k * LPL + off);
                    oacc[0][k] = __builtin_amdgcn_mfma_i32_16x16x64_i8(a0c, bo, oacc[0][k], 0, 0, 0);
                    oacc[1][k] = __builtin_amdgcn_mfma_i32_16x16x64_i8(a1c, bo, oacc[1][k], 0, 0, 0);
                }
                a0c = a0n; a1c = a1n; a0n = a0f; a1n = a1f;
            }

            if (col < ONUM) {
                #pragma clang fp contract(off)
                const bool msk = (t - 1) >= TENC;
                #pragma unroll
                for (int a = 0; a < 2; ++a) {
                    #pragma unroll
                    for (int r = 0; r < 4; ++r) {
                        int64_t tot = ((int64_t)oacc[a][3][r] << 24)
                                    + ((int64_t)oacc[a][2][r] << 16)
                                    + ((int64_t)oacc[a][1][r] << 8)
                                    +  (int64_t)oacc[a][0][r];
                        float o_in = ((float)((double)tot * INV32)) + boO;
                        float osp_ = osp[a][r];
                        float bnew = (roO * obb[a][r]) + ((1.0f - roO) * osp_);
                        float B = 0.01f + (1.8f * bnew);
                        float mem = ((om[a][r] * alpha) + (onem * o_in)) - (B * osp_);
                        float s = (mem - B) > 0.f ? 1.f : 0.f;
                        obb[a][r] = bnew; om[a][r] = mem; osp[a][r] = s;
                        if (msk) cnt[a][r] += s;
                    }
                }
            }
        }

        if (t < TTOT) grid_barrier();
    }

    // ---- write spike counts ----
    if (is_o && col < ONUM) {
        #pragma unroll
        for (int a = 0; a < 2; ++a)
            #pragma unroll
            for (int r = 0; r < 4; ++r) {
                int n = n0 + a * 16 + quad * 4 + r;
                out[(size_t)n * ONUM + col] = cnt[a][r];
            }
    }
}

// ---------------------------------------------------------------------------
extern "C" void kernel_launch(void* const* d_in, const int* in_sizes, int n_in,
                              void* d_out, int out_size, void* d_ws, size_t ws_size,
                              hipStream_t stream)
{
    const float* x      = (const float*)d_in[0];
    const float* Wi     = (const float*)d_in[1];
    const float* b_i2h  = (const float*)d_in[2];
    const float* Wh     = (const float*)d_in[3];
    const float* b_h2h  = (const float*)d_in[4];
    const float* Wo     = (const float*)d_in[5];
    const float* b_h2o  = (const float*)d_in[6];
    const float* tau_h  = (const float*)d_in[7];
    const float* tau_o  = (const float*)d_in[8];
    float* out = (float*)d_out;

    uintptr_t p = (uintptr_t)d_ws;
    p = (p + 255) & ~(uintptr_t)255;
    int8_t* spk0 = (int8_t*)p; p += (size_t)N_ * SROW;
    p = (p + 255) & ~(uintptr_t)255;
    int8_t* spk1 = (int8_t*)p;

    (void)hipFuncSetAttribute((const void*)lsnn_persist,
                              hipFuncAttributeMaxDynamicSharedMemorySize, SMEM_TOT);
    lsnn_persist<<<NBLK, 512, SMEM_TOT, stream>>>(
        x, Wi, b_i2h, Wh, b_h2h, Wo, b_h2o, tau_h, tau_o, spk0, spk1, out);
}

// Round 7
// 2379.887 us; speedup vs baseline: 1.3895x; 1.3895x over previous
//
#include <hip/hip_runtime.h>
#include <math.h>
#include <stdint.h>

namespace {
constexpr int N_    = 2048;
constexpr int H_    = 800;
constexpr int IN_   = 28;
constexpr int TENC  = 28;
constexpr int TTOT  = 78;             // 28 encode + 50 decode
constexpr int ONUM  = 10;
constexpr int HBLK  = 200;            // 25 it-tiles x 8 ngroups
constexpr int NBLK  = 208;            // + 8 output blocks
constexpr int PSTR  = 128;            // packed spike row stride (bytes); 104 used
constexpr int NSEG  = 13 * 4 * 2;     // (c, digit k, neuron-half) B segments
constexpr int SMEM_B = NSEG * 1024;   // 106496 B: fragment-ordered digit planes
constexpr int SMEM_W = IN_ * 32 * 4;  // 3584 B: Wi tile
constexpr int SMEM_TOT = SMEM_B + SMEM_W;  // 110080 <= 160K -> 1 block/CU
}

typedef __attribute__((ext_vector_type(4))) int v4i;

// balanced base-256 digits of round(w * 2^32); exact for |w| < ~0.49
__device__ __forceinline__ void digitize(float w, int8_t d[4]) {
    double dd = (double)w * 4294967296.0;
    long long r = (long long)rint(dd);
    int8_t d0 = (int8_t)(r & 255); r = (r - (long long)d0) >> 8;
    int8_t d1 = (int8_t)(r & 255); r = (r - (long long)d1) >> 8;
    int8_t d2 = (int8_t)(r & 255); r = (r - (long long)d2) >> 8;
    long long r3 = r; r3 = r3 > 127 ? 127 : (r3 < -128 ? -128 : r3);
    d[0] = d0; d[1] = d1; d[2] = d2; d[3] = (int8_t)r3;
}

// expand 16 spike bits -> 16 bytes (0/1) as v4i
__device__ __forceinline__ v4i unpack16(uint32_t u) {
    v4i f;
    f[0] = (int)((((u      ) & 0xFu) * 0x00204081u) & 0x01010101u);
    f[1] = (int)((((u >>  4) & 0xFu) * 0x00204081u) & 0x01010101u);
    f[2] = (int)((((u >>  8) & 0xFu) * 0x00204081u) & 0x01010101u);
    f[3] = (int)((((u >> 12) & 0xFu) * 0x00204081u) & 0x01010101u);
    return f;
}

// --------------------------- grid barrier (proven in r6) --------------------
__device__ unsigned g_bar_cnt = 0;
__device__ unsigned g_bar_gen = 0;

__device__ __forceinline__ void grid_barrier() {
    __syncthreads();
    if (threadIdx.x == 0) {
        unsigned gen = __hip_atomic_load(&g_bar_gen, __ATOMIC_RELAXED, __HIP_MEMORY_SCOPE_AGENT);
        unsigned arr = __hip_atomic_fetch_add(&g_bar_cnt, 1u, __ATOMIC_ACQ_REL, __HIP_MEMORY_SCOPE_AGENT);
        if (arr == (unsigned)(NBLK - 1)) {
            __hip_atomic_store(&g_bar_cnt, 0u, __ATOMIC_RELAXED, __HIP_MEMORY_SCOPE_AGENT);
            __hip_atomic_fetch_add(&g_bar_gen, 1u, __ATOMIC_RELEASE, __HIP_MEMORY_SCOPE_AGENT);
        } else {
            while (__hip_atomic_load(&g_bar_gen, __ATOMIC_RELAXED, __HIP_MEMORY_SCOPE_AGENT) == gen)
                __builtin_amdgcn_s_sleep(8);
            (void)__hip_atomic_load(&g_bar_gen, __ATOMIC_ACQUIRE, __HIP_MEMORY_SCOPE_AGENT);
        }
    }
    __syncthreads();
}

// ---------------------------------------------------------------------------
// prepass: transpose x into xt2[t][n][c] (contiguous 28 floats per sample) and
// zero the packed spike buffers.
// ---------------------------------------------------------------------------
__global__ void prep_kernel(const float* __restrict__ x, float* __restrict__ xt2,
                            uint32_t* __restrict__ sp0, uint32_t* __restrict__ sp1)
{
    size_t idx = (size_t)blockIdx.x * blockDim.x + threadIdx.x;
    size_t stride = (size_t)gridDim.x * blockDim.x;
    const size_t TOT = (size_t)TENC * N_ * IN_;
    for (size_t e = idx; e < TOT; e += stride) {
        int t = (int)(e / (N_ * IN_));
        int rem = (int)(e % (N_ * IN_));
        int n = rem / IN_, c = rem % IN_;
        xt2[e] = x[(size_t)n * 784 + c * TENC + t];
    }
    const size_t PW = (size_t)N_ * PSTR / 4;
    for (size_t e = idx; e < PW; e += stride) { sp0[e] = 0u; sp1[e] = 0u; }
}

// ---------------------------------------------------------------------------
// Persistent LSNN: 200 hidden blocks (32 neurons x 256 samples) + 8 o-blocks.
// B digit planes in LDS (fragment order), spikes bit-packed in global,
// hm/hb/o-state in registers.
// ---------------------------------------------------------------------------
__global__ __launch_bounds__(512, 2)
void lsnn_persist(const float* __restrict__ xt2,
                  const float* __restrict__ Wi,
                  const float* __restrict__ b_i2h,
                  const float* __restrict__ Wh,
                  const float* __restrict__ b_h2h,
                  const float* __restrict__ Wo,
                  const float* __restrict__ b_h2o,
                  const float* __restrict__ tau_h,
                  const float* __restrict__ tau_o,
                  uint8_t* sp0, uint8_t* sp1,
                  float* __restrict__ out)
{
    extern __shared__ __align__(16) int8_t smem[];
    int8_t* Bl = smem;                       // [NSEG][64 lanes][16 B]
    float*  wl = (float*)(smem + SMEM_B);    // [28][32]

    const int bid  = blockIdx.x;
    const bool is_o = (bid >= HBLK);
    const int it   = is_o ? 0 : (bid % 25);
    const int ng   = is_o ? (bid - HBLK) : (bid / 25);
    const int i0   = it * 32;
    const int wv   = threadIdx.x >> 6;
    const int lane = threadIdx.x & 63;
    const int quad = lane >> 4;
    const int col  = lane & 15;
    const int n0   = ng * 256 + wv * 32;

    // ---- build B digit fragments in LDS (once) ----
    for (int e = threadIdx.x; e < 13 * 2 * 64; e += 512) {
        int c  = e >> 7;           // 0..12
        int bh = (e >> 6) & 1;     // neuron half
        int ln = e & 63;
        int q  = ln >> 4, cl = ln & 15;
        int kbase = c * 64 + q * 16;
        uint32_t w4[4][4] = {};
        int row = bh * 16 + cl;
        #pragma unroll
        for (int j = 0; j < 16; ++j) {
            int kidx = kbase + j;
            float w = 0.f;
            if (kidx < H_) {
                if (!is_o) w = Wh[(size_t)(i0 + row) * H_ + kidx];
                else if (bh == 0 && cl < ONUM) w = Wo[(size_t)cl * H_ + kidx];
            }
            int8_t d[4]; digitize(w, d);
            #pragma unroll
            for (int k = 0; k < 4; ++k)
                w4[k][j >> 2] |= ((uint32_t)(uint8_t)d[k]) << ((j & 3) * 8);
        }
        #pragma unroll
        for (int k = 0; k < 4; ++k) {
            v4i v; v[0] = (int)w4[k][0]; v[1] = (int)w4[k][1];
            v[2] = (int)w4[k][2]; v[3] = (int)w4[k][3];
            *(v4i*)(Bl + (((c * 8) + k * 2 + bh) << 10) + (ln << 4)) = v;
        }
    }
    if (!is_o) {
        for (int e = threadIdx.x; e < IN_ * 32; e += 512) {
            int c = e >> 5, il = e & 31;
            wl[c * 32 + il] = Wi[(size_t)(i0 + il) * IN_ + c];
        }
    }

    // ---- per-lane constants & register state ----
    const float alpha = (float)exp((double)(-1.0f / 20.0f));
    const float onem  = 1.0f - alpha;
    const double INV32 = 1.0 / 4294967296.0;

    float hm[2][2][4] = {}, hbv[2][2][4], psp[2][2][4] = {};
    float roB[2] = {}, biB[2] = {}, bhB[2] = {};
    float om[2][4] = {}, osp[2][4] = {}, obb[2][4], cnt[2][4] = {};
    float roO = 0.f, boO = 0.f;

    if (!is_o) {
        #pragma unroll
        for (int b = 0; b < 2; ++b) {
            int i = i0 + b * 16 + col;
            float arg = -1.0f / tau_h[i];
            roB[b] = (float)exp((double)arg);
            biB[b] = b_i2h[i]; bhB[b] = b_h2h[i];
        }
        #pragma unroll
        for (int a = 0; a < 2; ++a)
            #pragma unroll
            for (int b = 0; b < 2; ++b)
                #pragma unroll
                for (int r = 0; r < 4; ++r) hbv[a][b][r] = 0.01f;
    } else {
        if (col < ONUM) {
            float arg = -1.0f / tau_o[col];
            roO = (float)exp((double)arg);
            boO = b_h2o[col];
        }
        #pragma unroll
        for (int a = 0; a < 2; ++a)
            #pragma unroll
            for (int r = 0; r < 4; ++r) obb[a][r] = 0.01f;
    }

    __syncthreads();
    grid_barrier();

    // ---- time loop ----
    for (int t = 0; t <= TTOT; ++t) {
        const uint8_t* rdP = (t & 1) ? sp1 : sp0;
        uint8_t*       wrP = (t & 1) ? sp0 : sp1;

        if (!is_o && t < TTOT) {
            // input projection (encode steps): fp64 exact, fp32-rounded once
            float inpf[2][2][4] = {};
            if (t < TENC) {
                #pragma unroll
                for (int a = 0; a < 2; ++a) {
                    #pragma unroll
                    for (int r = 0; r < 4; ++r) {
                        int n = n0 + a * 16 + quad * 4 + r;
                        const float* xp = xt2 + ((size_t)t * N_ + n) * IN_;
                        double s0 = 0.0, s1 = 0.0;
                        #pragma unroll
                        for (int c = 0; c < IN_; ++c) {
                            double xv = (double)xp[c];
                            s0 += xv * (double)wl[c * 32 + col];
                            s1 += xv * (double)wl[c * 32 + 16 + col];
                        }
                        inpf[a][0][r] = (float)s0;
                        inpf[a][1][r] = (float)s1;
                    }
                }
            }

            // preload this wave's packed A rows (13 ushorts x 2 rows)
            const uint8_t* r0 = rdP + (size_t)(n0 + col) * PSTR + quad * 2;
            const uint8_t* r1 = rdP + (size_t)(n0 + 16 + col) * PSTR + quad * 2;
            uint16_t u0[13], u1[13];
            #pragma unroll
            for (int c = 0; c < 13; ++c) {
                u0[c] = *(const uint16_t*)(r0 + c * 8);
                u1[c] = *(const uint16_t*)(r1 + c * 8);
            }

            v4i acc4[2][2][4] = {};
            #pragma unroll
            for (int c = 0; c < 13; ++c) {
                v4i a0 = unpack16((uint32_t)u0[c]);
                v4i a1 = unpack16((uint32_t)u1[c]);
                #pragma unroll
                for (int k = 0; k < 4; ++k) {
                    v4i b0 = *(const v4i*)(Bl + (((c * 8) + k * 2 + 0) << 10) + (lane << 4));
                    v4i b1 = *(const v4i*)(Bl + (((c * 8) + k * 2 + 1) << 10) + (lane << 4));
                    acc4[0][0][k] = __builtin_amdgcn_mfma_i32_16x16x64_i8(a0, b0, acc4[0][0][k], 0, 0, 0);
                    acc4[0][1][k] = __builtin_amdgcn_mfma_i32_16x16x64_i8(a0, b1, acc4[0][1][k], 0, 0, 0);
                    acc4[1][0][k] = __builtin_amdgcn_mfma_i32_16x16x64_i8(a1, b0, acc4[1][0][k], 0, 0, 0);
                    acc4[1][1][k] = __builtin_amdgcn_mfma_i32_16x16x64_i8(a1, b1, acc4[1][1][k], 0, 0, 0);
                }
            }

            // hidden epilogue: fp32, reference order, no FMA
            {
                #pragma clang fp contract(off)
                #pragma unroll
                for (int a = 0; a < 2; ++a) {
                    #pragma unroll
                    for (int b = 0; b < 2; ++b) {
                        #pragma unroll
                        for (int r = 0; r < 4; ++r) {
                            int64_t tot = ((int64_t)acc4[a][b][3][r] << 24)
                                        + ((int64_t)acc4[a][b][2][r] << 16)
                                        + ((int64_t)acc4[a][b][1][r] << 8)
                                        +  (int64_t)acc4[a][b][0][r];
                            float rec = (float)((double)tot * INV32);
                            float h_in = ((inpf[a][b][r] + biB[b]) + rec) + bhB[b];
                            float sp = psp[a][b][r];
                            float ro = roB[b];
                            float bnew = (ro * hbv[a][b][r]) + ((1.0f - ro) * sp);
                            float B = 0.01f + (1.8f * bnew);
                            float mem = ((hm[a][b][r] * alpha) + (onem * h_in)) - (B * sp);
                            float s = (mem - B) > 0.f ? 1.f : 0.f;
                            hbv[a][b][r] = bnew; hm[a][b][r] = mem; psp[a][b][r] = s;
                        }
                    }
                }
            }

            // pack spikes: ballots -> one 32-bit word per row (this block's i-tile)
            #pragma unroll
            for (int a = 0; a < 2; ++a) {
                #pragma unroll
                for (int r = 0; r < 4; ++r) {
                    unsigned long long bal0 = __ballot(psp[a][0][r] > 0.5f);
                    unsigned long long bal1 = __ballot(psp[a][1][r] > 0.5f);
                    if (col == a * 4 + r) {
                        uint32_t w = (uint32_t)((bal0 >> (quad * 16)) & 0xFFFFull)
                                   | ((uint32_t)((bal1 >> (quad * 16)) & 0xFFFFull) << 16);
                        int n = n0 + a * 16 + quad * 4 + r;
                        *(uint32_t*)(wrP + (size_t)n * PSTR + it * 4) = w;
                    }
                }
            }
        }

        if (is_o && t >= 1) {
            const uint8_t* r0 = rdP + (size_t)(n0 + col) * PSTR + quad * 2;
            const uint8_t* r1 = rdP + (size_t)(n0 + 16 + col) * PSTR + quad * 2;
            uint16_t u0[13], u1[13];
            #pragma unroll
            for (int c = 0; c < 13; ++c) {
                u0[c] = *(const uint16_t*)(r0 + c * 8);
                u1[c] = *(const uint16_t*)(r1 + c * 8);
            }
            v4i oacc[2][4] = {};
            #pragma unroll
            for (int c = 0; c < 13; ++c) {
                v4i a0 = unpack16((uint32_t)u0[c]);
                v4i a1 = unpack16((uint32_t)u1[c]);
                #pragma unroll
                for (int k = 0; k < 4; ++k) {
                    v4i bo = *(const v4i*)(Bl + (((c * 8) + k * 2 + 0) << 10) + (lane << 4));
                    oacc[0][k] = __builtin_amdgcn_mfma_i32_16x16x64_i8(a0, bo, oacc[0][k], 0, 0, 0);
                    oacc[1][k] = __builtin_amdgcn_mfma_i32_16x16x64_i8(a1, bo, oacc[1][k], 0, 0, 0);
                }
            }
            if (col < ONUM) {
                #pragma clang fp contract(off)
                const bool msk = (t - 1) >= TENC;
                #pragma unroll
                for (int a = 0; a < 2; ++a) {
                    #pragma unroll
                    for (int r = 0; r < 4; ++r) {
                        int64_t tot = ((int64_t)oacc[a][3][r] << 24)
                                    + ((int64_t)oacc[a][2][r] << 16)
                                    + ((int64_t)oacc[a][1][r] << 8)
                                    +  (int64_t)oacc[a][0][r];
                        float o_in = ((float)((double)tot * INV32)) + boO;
                        float osp_ = osp[a][r];
                        float bnew = (roO * obb[a][r]) + ((1.0f - roO) * osp_);
                        float B = 0.01f + (1.8f * bnew);
                        float mem = ((om[a][r] * alpha) + (onem * o_in)) - (B * osp_);
                        float s = (mem - B) > 0.f ? 1.f : 0.f;
                        obb[a][r] = bnew; om[a][r] = mem; osp[a][r] = s;
                        if (msk) cnt[a][r] += s;
                    }
                }
            }
        }

        if (t < TTOT) grid_barrier();
    }

    // ---- write spike counts ----
    if (is_o && col < ONUM) {
        #pragma unroll
        for (int a = 0; a < 2; ++a)
            #pragma unroll
            for (int r = 0; r < 4; ++r) {
                int n = n0 + a * 16 + quad * 4 + r;
                out[(size_t)n * ONUM + col] = cnt[a][r];
            }
    }
}

// ---------------------------------------------------------------------------
extern "C" void kernel_launch(void* const* d_in, const int* in_sizes, int n_in,
                              void* d_out, int out_size, void* d_ws, size_t ws_size,
                              hipStream_t stream)
{
    const float* x      = (const float*)d_in[0];
    const float* Wi     = (const float*)d_in[1];
    const float* b_i2h  = (const float*)d_in[2];
    const float* Wh     = (const float*)d_in[3];
    const float* b_h2h  = (const float*)d_in[4];
    const float* Wo     = (const float*)d_in[5];
    const float* b_h2o  = (const float*)d_in[6];
    const float* tau_h  = (const float*)d_in[7];
    const float* tau_o  = (const float*)d_in[8];
    float* out = (float*)d_out;

    uintptr_t p = (uintptr_t)d_ws;
    auto alloc = [&](size_t bytes) -> void* {
        p = (p + 255) & ~(uintptr_t)255;
        void* r = (void*)p; p += bytes; return r;
    };
    uint8_t* sp0 = (uint8_t*)alloc((size_t)N_ * PSTR);
    uint8_t* sp1 = (uint8_t*)alloc((size_t)N_ * PSTR);
    float*   xt2 = (float*)alloc((size_t)TENC * N_ * IN_ * 4);

    prep_kernel<<<1024, 256, 0, stream>>>(x, xt2, (uint32_t*)sp0, (uint32_t*)sp1);

    (void)hipFuncSetAttribute((const void*)lsnn_persist,
                              hipFuncAttributeMaxDynamicSharedMemorySize, SMEM_TOT);
    lsnn_persist<<<NBLK, 512, SMEM_TOT, stream>>>(
        xt2, Wi, b_i2h, Wh, b_h2h, Wo, b_h2o, tau_h, tau_o, sp0, sp1, out);
}